// Round 1
// baseline (11827.767 us; speedup 1.0000x reference)
//
#include <hip/hip_runtime.h>
#include <hip/hip_bf16.h>
#include <cstdint>

#define N_NODES 50000
#define E_EDGES 800000
#define R_REL   3
#define IN_F    128
#define HID_F   128
#define D_F     384
#define H_HEADS 8
#define O_PER   16
#define OUT_F   64
#define L_LAYERS 4

// ---- float atomicMax encoding (monotonic uint mapping) ----
__device__ __forceinline__ unsigned encf(float f) {
    unsigned u = __float_as_uint(f);
    return (u & 0x80000000u) ? ~u : (u | 0x80000000u);
}
__device__ __forceinline__ float decf(unsigned u) {
    return __uint_as_float((u & 0x80000000u) ? (u ^ 0x80000000u) : ~u);
}

// =====================================================================
// Generic fp32 register-tiled GEMM: C[M,Nc] = A[M,K] @ B[K,Nc]
// NORM: A-element transform a -> relu(a*scale[k] + bias[k])  (fused BN+ReLU)
// BM=128 BN=64 BK=16 TM=8 TN=4, 256 threads.
// =====================================================================
template<bool NORM>
__global__ __launch_bounds__(256) void gemm_kernel(
    const float* __restrict__ A, const float* __restrict__ B, float* __restrict__ C,
    int M, int Nc, int K,
    const float* __restrict__ nscale, const float* __restrict__ nbias)
{
    constexpr int BM = 128, BN = 64, BK = 16, TM = 8, TN = 4;
    __shared__ float As[BK][BM + 4];   // +4 pad: store conflicts 2-way (free)
    __shared__ float Bs[BK][BN];

    const int t = threadIdx.x;
    const int row0 = blockIdx.x * BM;
    const int col0 = blockIdx.y * BN;
    const int trow = t >> 4;          // 0..15
    const int tcol = t & 15;          // 0..15

    float acc[TM][TN] = {};

    const int ar = t >> 2;            // A-load row within tile (first half)
    const int akq = t & 3;            // A-load k-quad

    for (int k0 = 0; k0 < K; k0 += BK) {
        // ---- load A tile (transposed into As[k][m]) ----
        #pragma unroll
        for (int half = 0; half < 2; ++half) {
            const int row = ar + half * 64;
            const int grow = row0 + row;
            float4 v = make_float4(0.f, 0.f, 0.f, 0.f);
            if (grow < M)
                v = *(const float4*)(A + (size_t)grow * K + k0 + akq * 4);
            if (NORM) {
                const float4 sc = *(const float4*)(nscale + k0 + akq * 4);
                const float4 bi = *(const float4*)(nbias + k0 + akq * 4);
                v.x = fmaxf(fmaf(v.x, sc.x, bi.x), 0.f);
                v.y = fmaxf(fmaf(v.y, sc.y, bi.y), 0.f);
                v.z = fmaxf(fmaf(v.z, sc.z, bi.z), 0.f);
                v.w = fmaxf(fmaf(v.w, sc.w, bi.w), 0.f);
            }
            As[akq * 4 + 0][row] = v.x;
            As[akq * 4 + 1][row] = v.y;
            As[akq * 4 + 2][row] = v.z;
            As[akq * 4 + 3][row] = v.w;
        }
        // ---- load B tile ----
        {
            const int krow = t >> 4, c4 = t & 15;
            const float4 v = *(const float4*)(B + (size_t)(k0 + krow) * Nc + col0 + c4 * 4);
            *(float4*)&Bs[krow][c4 * 4] = v;
        }
        __syncthreads();
        #pragma unroll
        for (int k = 0; k < BK; ++k) {
            const float4 a0 = *(const float4*)&As[k][trow * TM];
            const float4 a1 = *(const float4*)&As[k][trow * TM + 4];
            const float4 b4 = *(const float4*)&Bs[k][tcol * TN];
            const float a[8] = {a0.x, a0.y, a0.z, a0.w, a1.x, a1.y, a1.z, a1.w};
            const float b[4] = {b4.x, b4.y, b4.z, b4.w};
            #pragma unroll
            for (int i = 0; i < TM; ++i)
                #pragma unroll
                for (int j = 0; j < TN; ++j)
                    acc[i][j] = fmaf(a[i], b[j], acc[i][j]);
        }
        __syncthreads();
    }
    #pragma unroll
    for (int i = 0; i < TM; ++i) {
        const int grow = row0 + trow * TM + i;
        if (grow < M) {
            float4 v = make_float4(acc[i][0], acc[i][1], acc[i][2], acc[i][3]);
            *(float4*)(C + (size_t)grow * Nc + col0 + tcol * TN) = v;
        }
    }
}

// =====================================================================
// BatchNorm stats: per-column sum & sumsq over rows (HID_F = 128 cols)
// =====================================================================
__global__ __launch_bounds__(256) void bn_stats_kernel(
    const float* __restrict__ tin, float* __restrict__ sums, int M)
{
    __shared__ float sb[256], qb[256];
    const int col = threadIdx.x & 127;
    const int half = threadIdx.x >> 7;
    const int r0 = blockIdx.x * 128;
    float s = 0.f, q = 0.f;
    #pragma unroll 4
    for (int i = 0; i < 64; ++i) {
        const int r = r0 + i * 2 + half;
        if (r < M) {
            const float v = tin[(size_t)r * 128 + col];
            s += v; q += v * v;
        }
    }
    sb[threadIdx.x] = s; qb[threadIdx.x] = q;
    __syncthreads();
    if (threadIdx.x < 128) {
        s = sb[threadIdx.x] + sb[threadIdx.x + 128];
        q = qb[threadIdx.x] + qb[threadIdx.x + 128];
        unsafeAtomicAdd(&sums[col], s);
        unsafeAtomicAdd(&sums[128 + col], q);
    }
}

__global__ void bn_final_kernel(
    const float* __restrict__ sums, const float* __restrict__ g,
    const float* __restrict__ b, float* __restrict__ scale,
    float* __restrict__ bias, float invN)
{
    const int c = threadIdx.x;
    const float mu = sums[c] * invN;
    const float var = sums[128 + c] * invN - mu * mu;
    const float rs = rsqrtf(var + 1e-5f);
    const float sc = g[c] * rs;
    scale[c] = sc;
    bias[c] = b[c] - mu * sc;
}

// =====================================================================
// el/er: one wave per node. el[n,h] = sum_o g[n,h,o]*al[h,o]
// =====================================================================
__global__ __launch_bounds__(256) void elr_kernel(
    const float* __restrict__ g, const float* __restrict__ al,
    const float* __restrict__ ar, float* __restrict__ el,
    float* __restrict__ er)
{
    const int wid = (blockIdx.x * 256 + threadIdx.x) >> 6;
    const int lane = threadIdx.x & 63;
    if (wid >= N_NODES) return;
    const int j = lane * 2;
    const float2 gv = *(const float2*)(g + (size_t)wid * 128 + j);
    const float2 av = *(const float2*)(al + j);
    const float2 bv = *(const float2*)(ar + j);
    float pl = gv.x * av.x + gv.y * av.y;
    float pr = gv.x * bv.x + gv.y * bv.y;
    #pragma unroll
    for (int m = 1; m < 8; m <<= 1) {
        pl += __shfl_xor(pl, m, 64);
        pr += __shfl_xor(pr, m, 64);
    }
    if ((lane & 7) == 0) {
        el[(size_t)wid * 8 + (lane >> 3)] = pl;
        er[(size_t)wid * 8 + (lane >> 3)] = pr;
    }
}

// =====================================================================
// Global max over edges of leaky_relu(el[src]+er[trg], 0.2)
// =====================================================================
__global__ __launch_bounds__(256) void edge_max_kernel(
    const int* __restrict__ src, const int* __restrict__ trg,
    const float* __restrict__ el, const float* __restrict__ er,
    unsigned* __restrict__ Menc)
{
    const int i = blockIdx.x * 256 + threadIdx.x;
    float m = -3.0e38f;
    if (i < E_EDGES) {
        const int s = src[i], t = trg[i];
        const float4 a0 = *(const float4*)(el + (size_t)s * 8);
        const float4 a1 = *(const float4*)(el + (size_t)s * 8 + 4);
        const float4 b0 = *(const float4*)(er + (size_t)t * 8);
        const float4 b1 = *(const float4*)(er + (size_t)t * 8 + 4);
        float v;
        v = a0.x + b0.x; v = v > 0.f ? v : 0.2f * v; m = fmaxf(m, v);
        v = a0.y + b0.y; v = v > 0.f ? v : 0.2f * v; m = fmaxf(m, v);
        v = a0.z + b0.z; v = v > 0.f ? v : 0.2f * v; m = fmaxf(m, v);
        v = a0.w + b0.w; v = v > 0.f ? v : 0.2f * v; m = fmaxf(m, v);
        v = a1.x + b1.x; v = v > 0.f ? v : 0.2f * v; m = fmaxf(m, v);
        v = a1.y + b1.y; v = v > 0.f ? v : 0.2f * v; m = fmaxf(m, v);
        v = a1.z + b1.z; v = v > 0.f ? v : 0.2f * v; m = fmaxf(m, v);
        v = a1.w + b1.w; v = v > 0.f ? v : 0.2f * v; m = fmaxf(m, v);
    }
    #pragma unroll
    for (int d = 1; d < 64; d <<= 1) m = fmaxf(m, __shfl_xor(m, d, 64));
    if ((threadIdx.x & 63) == 0) atomicMax(Menc, encf(m));
}

// =====================================================================
// Fused edge pass: one wave per edge.
//   e_h = exp(leaky(el[src,h]+er[trg,h],0.2) - M)
//   hnum[trg, rbase + j] += g[src, j] * e_h      (j = 0..127, h = j/16)
//   denom[trg, h] += e_h
// =====================================================================
__global__ __launch_bounds__(256) void edge_pass_kernel(
    const int* __restrict__ src, const int* __restrict__ trg,
    const float* __restrict__ g, const float* __restrict__ el,
    const float* __restrict__ er, const unsigned* __restrict__ Menc,
    float* __restrict__ denom, float* __restrict__ hnum, int rbase)
{
    const float M = decf(*Menc);
    const int lane = threadIdx.x & 63;
    const int h = lane >> 3;
    const int j = lane * 2;
    int wid = (blockIdx.x * 256 + threadIdx.x) >> 6;
    const int nw = (gridDim.x * 256) >> 6;
    for (; wid < E_EDGES; wid += nw) {
        const int s = src[wid], t = trg[wid];
        float sc = el[(size_t)s * 8 + h] + er[(size_t)t * 8 + h];
        sc = sc > 0.f ? sc : 0.2f * sc;
        const float ex = __expf(sc - M);
        const float2 gv = *(const float2*)(g + (size_t)s * 128 + j);
        float* o = hnum + (size_t)t * 384 + rbase + j;
        unsafeAtomicAdd(o, gv.x * ex);
        unsafeAtomicAdd(o + 1, gv.y * ex);
        if ((lane & 7) == 0) unsafeAtomicAdd(denom + (size_t)t * 8 + h, ex);
    }
}

// =====================================================================
// combine: h = leaky(hnum / (denom+1e-16), 0.01) + x
// =====================================================================
__global__ __launch_bounds__(256) void combine_kernel(
    const float* __restrict__ hnum, const float* __restrict__ denom,
    const float* __restrict__ x, float* __restrict__ h)
{
    const int i = blockIdx.x * 256 + threadIdx.x;
    if (i >= N_NODES * 96) return;
    const int n = i / 96;
    const int j = (i - n * 96) * 4;
    const int r = j >> 7;
    const int hh = (j & 127) >> 4;
    const float d = denom[((size_t)r * N_NODES + n) * 8 + hh];
    const float inv = 1.0f / (d + 1e-16f);
    const float4 num = *(const float4*)(hnum + (size_t)n * 384 + j);
    const float4 xv = *(const float4*)(x + (size_t)n * 384 + j);
    float4 o; float v;
    v = num.x * inv; o.x = (v > 0.f ? v : 0.01f * v) + xv.x;
    v = num.y * inv; o.y = (v > 0.f ? v : 0.01f * v) + xv.y;
    v = num.z * inv; o.z = (v > 0.f ? v : 0.01f * v) + xv.z;
    v = num.w * inv; o.w = (v > 0.f ? v : 0.01f * v) + xv.w;
    *(float4*)(h + (size_t)n * 384 + j) = o;
}

// =====================================================================
extern "C" void kernel_launch(void* const* d_in, const int* in_sizes, int n_in,
                              void* d_out, int out_size, void* d_ws, size_t ws_size,
                              hipStream_t stream) {
    const float* inputs = (const float*)d_in[0];
    const int*   edges  = (const int*)d_in[1];
    const float* W_emb1 = (const float*)d_in[2];
    const float* W_emb2 = (const float*)d_in[3];
    const float* g_emb  = (const float*)d_in[4];
    const float* b_emb  = (const float*)d_in[5];
    const float* Wg     = (const float*)d_in[6];
    const float* al     = (const float*)d_in[7];
    const float* ar     = (const float*)d_in[8];
    const float* W_d1   = (const float*)d_in[9];
    const float* W_d2   = (const float*)d_in[10];
    const float* g_d    = (const float*)d_in[11];
    const float* b_d    = (const float*)d_in[12];
    float* out = (float*)d_out;

    // workspace layout (floats); hnum and denom must stay contiguous (one memset)
    float* w = (float*)d_ws;
    float* x     = w; w += (size_t)N_NODES * D_F;
    float* h     = w; w += (size_t)N_NODES * D_F;
    float* hnum  = w; w += (size_t)N_NODES * D_F;
    float* denom = w; w += (size_t)R_REL * N_NODES * H_HEADS;
    float* t1    = w; w += (size_t)N_NODES * HID_F;
    float* el    = w; w += (size_t)N_NODES * H_HEADS;
    float* er    = w; w += (size_t)N_NODES * H_HEADS;
    float* sums  = w; w += 256;
    float* scale = w; w += 128;
    float* bias  = w; w += 128;
    unsigned* Menc = (unsigned*)w;

    auto gemm = [&](const float* A, const float* B, float* C, int M, int Nc, int K,
                    const float* sc, const float* bi) {
        dim3 grid((M + 127) / 128, Nc / 64);
        if (sc)
            gemm_kernel<true><<<grid, 256, 0, stream>>>(A, B, C, M, Nc, K, sc, bi);
        else
            gemm_kernel<false><<<grid, 256, 0, stream>>>(A, B, C, M, Nc, K, nullptr, nullptr);
    };

    // ---- Embedding MLP: x = relu(BN(inputs@W_emb1)) @ W_emb2 ----
    gemm(inputs, W_emb1, t1, N_NODES, HID_F, IN_F, nullptr, nullptr);
    hipMemsetAsync(sums, 0, 256 * sizeof(float), stream);
    bn_stats_kernel<<<(N_NODES + 127) / 128, 256, 0, stream>>>(t1, sums, N_NODES);
    bn_final_kernel<<<1, 128, 0, stream>>>(sums, g_emb, b_emb, scale, bias, 1.0f / N_NODES);
    gemm(t1, W_emb2, x, N_NODES, D_F, HID_F, scale, bias);
    hipMemcpyAsync(h, x, (size_t)N_NODES * D_F * sizeof(float),
                   hipMemcpyDeviceToDevice, stream);

    // ---- GAT layers ----
    for (int l = 0; l < L_LAYERS; ++l) {
        hipMemsetAsync(hnum, 0,
                       ((size_t)N_NODES * D_F + (size_t)R_REL * N_NODES * H_HEADS) * sizeof(float),
                       stream);
        for (int r = 0; r < R_REL; ++r) {
            const int* srcp = edges + (size_t)r * 2 * E_EDGES;
            const int* trgp = srcp + E_EDGES;
            const int lr = l * R_REL + r;
            gemm(h, Wg + (size_t)lr * D_F * (H_HEADS * O_PER), t1, N_NODES,
                 H_HEADS * O_PER, D_F, nullptr, nullptr);
            elr_kernel<<<(N_NODES + 3) / 4, 256, 0, stream>>>(
                t1, al + lr * (H_HEADS * O_PER), ar + lr * (H_HEADS * O_PER), el, er);
            hipMemsetAsync(Menc, 0, 4, stream);
            edge_max_kernel<<<(E_EDGES + 255) / 256, 256, 0, stream>>>(srcp, trgp, el, er, Menc);
            edge_pass_kernel<<<8192, 256, 0, stream>>>(
                srcp, trgp, t1, el, er, Menc,
                denom + (size_t)r * N_NODES * H_HEADS, hnum, r * 128);
        }
        combine_kernel<<<(N_NODES * 96 + 255) / 256, 256, 0, stream>>>(hnum, denom, x, h);
    }

    // ---- Decoder MLP: out = relu(BN(h@W_d1)) @ W_d2 ----
    gemm(h, W_d1, t1, N_NODES, HID_F, D_F, nullptr, nullptr);
    hipMemsetAsync(sums, 0, 256 * sizeof(float), stream);
    bn_stats_kernel<<<(N_NODES + 127) / 128, 256, 0, stream>>>(t1, sums, N_NODES);
    bn_final_kernel<<<1, 128, 0, stream>>>(sums, g_d, b_d, scale, bias, 1.0f / N_NODES);
    gemm(t1, W_d2, out, N_NODES, OUT_F, HID_F, scale, bias);
}

// Round 2
// 4591.998 us; speedup vs baseline: 2.5757x; 2.5757x over previous
//
#include <hip/hip_runtime.h>
#include <hip/hip_bf16.h>
#include <cstdint>

#define N_NODES 50000
#define E_EDGES 800000
#define R_REL   3
#define IN_F    128
#define HID_F   128
#define D_F     384
#define H_HEADS 8
#define O_PER   16
#define OUT_F   64
#define L_LAYERS 4

// ---- float atomicMax encoding (monotonic uint mapping) ----
__device__ __forceinline__ unsigned encf(float f) {
    unsigned u = __float_as_uint(f);
    return (u & 0x80000000u) ? ~u : (u | 0x80000000u);
}
__device__ __forceinline__ float decf(unsigned u) {
    return __uint_as_float((u & 0x80000000u) ? (u ^ 0x80000000u) : ~u);
}

// =====================================================================
// Generic fp32 register-tiled GEMM: C[M,Nc] = A[M,K] @ B[K,Nc]
// NORM: A-element transform a -> relu(a*scale[k] + bias[k])  (fused BN+ReLU)
// BM=128 BN=64 BK=16 TM=8 TN=4, 256 threads.
// =====================================================================
template<bool NORM>
__global__ __launch_bounds__(256) void gemm_kernel(
    const float* __restrict__ A, const float* __restrict__ B, float* __restrict__ C,
    int M, int Nc, int K,
    const float* __restrict__ nscale, const float* __restrict__ nbias)
{
    constexpr int BM = 128, BN = 64, BK = 16, TM = 8, TN = 4;
    __shared__ float As[BK][BM + 4];
    __shared__ float Bs[BK][BN];

    const int t = threadIdx.x;
    const int row0 = blockIdx.x * BM;
    const int col0 = blockIdx.y * BN;
    const int trow = t >> 4;
    const int tcol = t & 15;

    float acc[TM][TN] = {};

    const int arow = t >> 2;
    const int akq = t & 3;

    for (int k0 = 0; k0 < K; k0 += BK) {
        #pragma unroll
        for (int half = 0; half < 2; ++half) {
            const int row = arow + half * 64;
            const int grow = row0 + row;
            float4 v = make_float4(0.f, 0.f, 0.f, 0.f);
            if (grow < M)
                v = *(const float4*)(A + (size_t)grow * K + k0 + akq * 4);
            if (NORM) {
                const float4 sc = *(const float4*)(nscale + k0 + akq * 4);
                const float4 bi = *(const float4*)(nbias + k0 + akq * 4);
                v.x = fmaxf(fmaf(v.x, sc.x, bi.x), 0.f);
                v.y = fmaxf(fmaf(v.y, sc.y, bi.y), 0.f);
                v.z = fmaxf(fmaf(v.z, sc.z, bi.z), 0.f);
                v.w = fmaxf(fmaf(v.w, sc.w, bi.w), 0.f);
            }
            As[akq * 4 + 0][row] = v.x;
            As[akq * 4 + 1][row] = v.y;
            As[akq * 4 + 2][row] = v.z;
            As[akq * 4 + 3][row] = v.w;
        }
        {
            const int krow = t >> 4, c4 = t & 15;
            const float4 v = *(const float4*)(B + (size_t)(k0 + krow) * Nc + col0 + c4 * 4);
            *(float4*)&Bs[krow][c4 * 4] = v;
        }
        __syncthreads();
        #pragma unroll
        for (int k = 0; k < BK; ++k) {
            const float4 a0 = *(const float4*)&As[k][trow * TM];
            const float4 a1 = *(const float4*)&As[k][trow * TM + 4];
            const float4 b4 = *(const float4*)&Bs[k][tcol * TN];
            const float a[8] = {a0.x, a0.y, a0.z, a0.w, a1.x, a1.y, a1.z, a1.w};
            const float b[4] = {b4.x, b4.y, b4.z, b4.w};
            #pragma unroll
            for (int i = 0; i < TM; ++i)
                #pragma unroll
                for (int j = 0; j < TN; ++j)
                    acc[i][j] = fmaf(a[i], b[j], acc[i][j]);
        }
        __syncthreads();
    }
    #pragma unroll
    for (int i = 0; i < TM; ++i) {
        const int grow = row0 + trow * TM + i;
        if (grow < M) {
            float4 v = make_float4(acc[i][0], acc[i][1], acc[i][2], acc[i][3]);
            *(float4*)(C + (size_t)grow * Nc + col0 + tcol * TN) = v;
        }
    }
}

// =====================================================================
// BatchNorm stats
// =====================================================================
__global__ __launch_bounds__(256) void bn_stats_kernel(
    const float* __restrict__ tin, float* __restrict__ sums, int M)
{
    __shared__ float sb[256], qb[256];
    const int col = threadIdx.x & 127;
    const int half = threadIdx.x >> 7;
    const int r0 = blockIdx.x * 128;
    float s = 0.f, q = 0.f;
    #pragma unroll 4
    for (int i = 0; i < 64; ++i) {
        const int r = r0 + i * 2 + half;
        if (r < M) {
            const float v = tin[(size_t)r * 128 + col];
            s += v; q += v * v;
        }
    }
    sb[threadIdx.x] = s; qb[threadIdx.x] = q;
    __syncthreads();
    if (threadIdx.x < 128) {
        s = sb[threadIdx.x] + sb[threadIdx.x + 128];
        q = qb[threadIdx.x] + qb[threadIdx.x + 128];
        unsafeAtomicAdd(&sums[col], s);
        unsafeAtomicAdd(&sums[128 + col], q);
    }
}

__global__ void bn_final_kernel(
    const float* __restrict__ sums, const float* __restrict__ g,
    const float* __restrict__ b, float* __restrict__ scale,
    float* __restrict__ bias, float invN)
{
    const int c = threadIdx.x;
    const float mu = sums[c] * invN;
    const float var = sums[128 + c] * invN - mu * mu;
    const float rs = rsqrtf(var + 1e-5f);
    const float sc = g[c] * rs;
    scale[c] = sc;
    bias[c] = b[c] - mu * sc;
}

// =====================================================================
// el/er: one wave per node
// =====================================================================
__global__ __launch_bounds__(256) void elr_kernel(
    const float* __restrict__ g, const float* __restrict__ al,
    const float* __restrict__ ar, float* __restrict__ el,
    float* __restrict__ er)
{
    const int wid = (blockIdx.x * 256 + threadIdx.x) >> 6;
    const int lane = threadIdx.x & 63;
    if (wid >= N_NODES) return;
    const int j = lane * 2;
    const float2 gv = *(const float2*)(g + (size_t)wid * 128 + j);
    const float2 av = *(const float2*)(al + j);
    const float2 bv = *(const float2*)(ar + j);
    float pl = gv.x * av.x + gv.y * av.y;
    float pr = gv.x * bv.x + gv.y * bv.y;
    #pragma unroll
    for (int m = 1; m < 8; m <<= 1) {
        pl += __shfl_xor(pl, m, 64);
        pr += __shfl_xor(pr, m, 64);
    }
    if ((lane & 7) == 0) {
        el[(size_t)wid * 8 + (lane >> 3)] = pl;
        er[(size_t)wid * 8 + (lane >> 3)] = pr;
    }
}

// =====================================================================
// Global max over edges of leaky_relu(el[src]+er[trg], 0.2)
// =====================================================================
__global__ __launch_bounds__(256) void edge_max_kernel(
    const int* __restrict__ src, const int* __restrict__ trg,
    const float* __restrict__ el, const float* __restrict__ er,
    unsigned* __restrict__ Menc)
{
    const int i = blockIdx.x * 256 + threadIdx.x;
    float m = -3.0e38f;
    if (i < E_EDGES) {
        const int s = src[i], t = trg[i];
        const float4 a0 = *(const float4*)(el + (size_t)s * 8);
        const float4 a1 = *(const float4*)(el + (size_t)s * 8 + 4);
        const float4 b0 = *(const float4*)(er + (size_t)t * 8);
        const float4 b1 = *(const float4*)(er + (size_t)t * 8 + 4);
        float v;
        v = a0.x + b0.x; v = v > 0.f ? v : 0.2f * v; m = fmaxf(m, v);
        v = a0.y + b0.y; v = v > 0.f ? v : 0.2f * v; m = fmaxf(m, v);
        v = a0.z + b0.z; v = v > 0.f ? v : 0.2f * v; m = fmaxf(m, v);
        v = a0.w + b0.w; v = v > 0.f ? v : 0.2f * v; m = fmaxf(m, v);
        v = a1.x + b1.x; v = v > 0.f ? v : 0.2f * v; m = fmaxf(m, v);
        v = a1.y + b1.y; v = v > 0.f ? v : 0.2f * v; m = fmaxf(m, v);
        v = a1.z + b1.z; v = v > 0.f ? v : 0.2f * v; m = fmaxf(m, v);
        v = a1.w + b1.w; v = v > 0.f ? v : 0.2f * v; m = fmaxf(m, v);
    }
    #pragma unroll
    for (int d = 1; d < 64; d <<= 1) m = fmaxf(m, __shfl_xor(m, d, 64));
    if ((threadIdx.x & 63) == 0) atomicMax(Menc, encf(m));
}

// =====================================================================
// CSR build: histogram -> scan -> scatter (by target)
// =====================================================================
__global__ __launch_bounds__(256) void hist_kernel(
    const int* __restrict__ trg, int* __restrict__ deg)
{
    const int i = blockIdx.x * 256 + threadIdx.x;
    if (i < E_EDGES) atomicAdd(&deg[trg[i]], 1);
}

__global__ __launch_bounds__(1024) void scan_kernel(
    const int* __restrict__ deg, int* __restrict__ rowptr, int* __restrict__ cursor)
{
    __shared__ int psum[1024];
    const int t = threadIdx.x;
    const int CH = (N_NODES + 1023) / 1024;  // 49
    const int base = t * CH;
    int s = 0;
    for (int i = 0; i < CH; ++i) {
        const int idx = base + i;
        if (idx < N_NODES) s += deg[idx];
    }
    psum[t] = s;
    __syncthreads();
    for (int off = 1; off < 1024; off <<= 1) {
        const int v = (t >= off) ? psum[t - off] : 0;
        __syncthreads();
        psum[t] += v;
        __syncthreads();
    }
    int run = (t == 0) ? 0 : psum[t - 1];
    for (int i = 0; i < CH; ++i) {
        const int idx = base + i;
        if (idx < N_NODES) { rowptr[idx] = run; cursor[idx] = run; run += deg[idx]; }
    }
    if (t == 1023) rowptr[N_NODES] = run;
}

__global__ __launch_bounds__(256) void scatter_kernel(
    const int* __restrict__ src, const int* __restrict__ trg,
    int* __restrict__ cursor, int* __restrict__ srcs)
{
    const int i = blockIdx.x * 256 + threadIdx.x;
    if (i < E_EDGES) {
        const int pos = atomicAdd(&cursor[trg[i]], 1);
        srcs[pos] = src[i];
    }
}

// =====================================================================
// Aggregation: one wave per target node. Gather g[src] rows, weight by
// exp(leaky(el[s]+er[t],0.2)-M), accumulate num+den in registers, then
// fuse alpha-divide + leaky(0.01) + residual(+x) into the h write.
// =====================================================================
__global__ __launch_bounds__(256) void agg_kernel(
    const int* __restrict__ rowptr, const int* __restrict__ srcs,
    const float* __restrict__ g, const float* __restrict__ el,
    const float* __restrict__ er, const unsigned* __restrict__ Menc,
    const float* __restrict__ x, float* __restrict__ hout, int rbase)
{
    const int wid = (blockIdx.x * 256 + threadIdx.x) >> 6;
    const int lane = threadIdx.x & 63;
    if (wid >= N_NODES) return;
    const int h = lane >> 3;
    const float M = decf(*Menc);
    const float erv = er[(size_t)wid * 8 + h];
    const int p0 = rowptr[wid], p1 = rowptr[wid + 1];
    float a0 = 0.f, a1 = 0.f, den = 0.f;
    for (int base = p0; base < p1; base += 64) {
        int sv = 0;
        if (base + lane < p1) sv = srcs[base + lane];
        const int nn = min(64, p1 - base);
        for (int j = 0; j < nn; ++j) {
            const int s = __shfl(sv, j, 64);
            float sc = el[(size_t)s * 8 + h] + erv;
            sc = sc > 0.f ? sc : 0.2f * sc;
            const float ex = __expf(sc - M);
            const float2 gv = *(const float2*)(g + (size_t)s * 128 + lane * 2);
            a0 = fmaf(gv.x, ex, a0);
            a1 = fmaf(gv.y, ex, a1);
            den += ex;
        }
    }
    const float inv = 1.f / (den + 1e-16f);
    const size_t o = (size_t)wid * 384 + rbase + lane * 2;
    float v0 = a0 * inv, v1 = a1 * inv;
    v0 = v0 > 0.f ? v0 : 0.01f * v0;
    v1 = v1 > 0.f ? v1 : 0.01f * v1;
    hout[o]     = v0 + x[o];
    hout[o + 1] = v1 + x[o + 1];
}

// =====================================================================
extern "C" void kernel_launch(void* const* d_in, const int* in_sizes, int n_in,
                              void* d_out, int out_size, void* d_ws, size_t ws_size,
                              hipStream_t stream) {
    const float* inputs = (const float*)d_in[0];
    const int*   edges  = (const int*)d_in[1];
    const float* W_emb1 = (const float*)d_in[2];
    const float* W_emb2 = (const float*)d_in[3];
    const float* g_emb  = (const float*)d_in[4];
    const float* b_emb  = (const float*)d_in[5];
    const float* Wg     = (const float*)d_in[6];
    const float* al     = (const float*)d_in[7];
    const float* ar     = (const float*)d_in[8];
    const float* W_d1   = (const float*)d_in[9];
    const float* W_d2   = (const float*)d_in[10];
    const float* g_d    = (const float*)d_in[11];
    const float* b_d    = (const float*)d_in[12];
    float* out = (float*)d_out;

    // ---- workspace layout ----
    float* w = (float*)d_ws;
    float* x     = w; w += (size_t)N_NODES * D_F;
    float* h     = w; w += (size_t)N_NODES * D_F;
    float* t1a   = w; w += (size_t)N_NODES * HID_F;
    float* t1b   = w; w += (size_t)N_NODES * HID_F;
    float* t1c   = w; w += (size_t)N_NODES * HID_F;
    float* el    = w; w += (size_t)R_REL * N_NODES * H_HEADS;
    float* er    = w; w += (size_t)R_REL * N_NODES * H_HEADS;
    float* sums  = w; w += 256;
    float* scale = w; w += 128;
    float* bias  = w; w += 128;
    unsigned* Menc = (unsigned*)w; w += 4;
    int* rowptr = (int*)w; w += (size_t)R_REL * (N_NODES + 1);
    int* srcs   = (int*)w; w += (size_t)R_REL * E_EDGES;
    int* deg    = (int*)w; w += N_NODES;
    int* cursor = (int*)w; w += N_NODES;
    float* t1s[3] = {t1a, t1b, t1c};

    auto gemm = [&](const float* A, const float* B, float* C, int M, int Nc, int K,
                    const float* sc, const float* bi) {
        dim3 grid((M + 127) / 128, Nc / 64);
        if (sc)
            gemm_kernel<true><<<grid, 256, 0, stream>>>(A, B, C, M, Nc, K, sc, bi);
        else
            gemm_kernel<false><<<grid, 256, 0, stream>>>(A, B, C, M, Nc, K, nullptr, nullptr);
    };

    // ---- Build CSR (by target) for each relation ----
    for (int r = 0; r < R_REL; ++r) {
        const int* srcp = edges + (size_t)r * 2 * E_EDGES;
        const int* trgp = srcp + E_EDGES;
        hipMemsetAsync(deg, 0, N_NODES * sizeof(int), stream);
        hist_kernel<<<(E_EDGES + 255) / 256, 256, 0, stream>>>(trgp, deg);
        scan_kernel<<<1, 1024, 0, stream>>>(deg, rowptr + (size_t)r * (N_NODES + 1), cursor);
        scatter_kernel<<<(E_EDGES + 255) / 256, 256, 0, stream>>>(
            srcp, trgp, cursor, srcs + (size_t)r * E_EDGES);
    }

    // ---- Embedding MLP: x = relu(BN(inputs@W_emb1)) @ W_emb2 ----
    gemm(inputs, W_emb1, t1a, N_NODES, HID_F, IN_F, nullptr, nullptr);
    hipMemsetAsync(sums, 0, 256 * sizeof(float), stream);
    bn_stats_kernel<<<(N_NODES + 127) / 128, 256, 0, stream>>>(t1a, sums, N_NODES);
    bn_final_kernel<<<1, 128, 0, stream>>>(sums, g_emb, b_emb, scale, bias, 1.0f / N_NODES);
    gemm(t1a, W_emb2, x, N_NODES, D_F, HID_F, scale, bias);
    hipMemcpyAsync(h, x, (size_t)N_NODES * D_F * sizeof(float),
                   hipMemcpyDeviceToDevice, stream);

    // ---- GAT layers ----
    for (int l = 0; l < L_LAYERS; ++l) {
        hipMemsetAsync(Menc, 0, R_REL * sizeof(unsigned), stream);
        for (int r = 0; r < R_REL; ++r) {
            const int* srcp = edges + (size_t)r * 2 * E_EDGES;
            const int* trgp = srcp + E_EDGES;
            const int lr = l * R_REL + r;
            gemm(h, Wg + (size_t)lr * D_F * (H_HEADS * O_PER), t1s[r], N_NODES,
                 H_HEADS * O_PER, D_F, nullptr, nullptr);
            elr_kernel<<<(N_NODES + 3) / 4, 256, 0, stream>>>(
                t1s[r], al + lr * (H_HEADS * O_PER), ar + lr * (H_HEADS * O_PER),
                el + (size_t)r * N_NODES * H_HEADS, er + (size_t)r * N_NODES * H_HEADS);
            edge_max_kernel<<<(E_EDGES + 255) / 256, 256, 0, stream>>>(
                srcp, trgp, el + (size_t)r * N_NODES * H_HEADS,
                er + (size_t)r * N_NODES * H_HEADS, Menc + r);
        }
        // h is only WRITTEN here (inputs are t1/el/er/x), so in-place is safe
        for (int r = 0; r < R_REL; ++r) {
            agg_kernel<<<(N_NODES * 64 + 255) / 256, 256, 0, stream>>>(
                rowptr + (size_t)r * (N_NODES + 1), srcs + (size_t)r * E_EDGES,
                t1s[r], el + (size_t)r * N_NODES * H_HEADS,
                er + (size_t)r * N_NODES * H_HEADS, Menc + r, x, h, r * 128);
        }
    }

    // ---- Decoder MLP: out = relu(BN(h@W_d1)) @ W_d2 ----
    gemm(h, W_d1, t1a, N_NODES, HID_F, D_F, nullptr, nullptr);
    hipMemsetAsync(sums, 0, 256 * sizeof(float), stream);
    bn_stats_kernel<<<(N_NODES + 127) / 128, 256, 0, stream>>>(t1a, sums, N_NODES);
    bn_final_kernel<<<1, 128, 0, stream>>>(sums, g_d, b_d, scale, bias, 1.0f / N_NODES);
    gemm(t1a, W_d2, out, N_NODES, OUT_F, HID_F, scale, bias);
}

// Round 3
// 2926.116 us; speedup vs baseline: 4.0421x; 1.5693x over previous
//
#include <hip/hip_runtime.h>
#include <hip/hip_bf16.h>
#include <cstdint>

#define N_NODES 50000
#define E_EDGES 800000
#define R_REL   3
#define IN_F    128
#define HID_F   128
#define D_F     384
#define H_HEADS 8
#define O_PER   16
#define OUT_F   64
#define L_LAYERS 4

// ---- float atomicMax encoding (monotonic uint mapping) ----
__device__ __forceinline__ unsigned encf(float f) {
    unsigned u = __float_as_uint(f);
    return (u & 0x80000000u) ? ~u : (u | 0x80000000u);
}
__device__ __forceinline__ float decf(unsigned u) {
    return __uint_as_float((u & 0x80000000u) ? (u ^ 0x80000000u) : ~u);
}

// =====================================================================
// Generic fp32 register-tiled GEMM: C[M,Nc] = A[M,K] @ B[K,Nc]
// NORM: A-element transform a -> relu(a*scale[k] + bias[k])  (fused BN+ReLU)
// BM=128 BN=64 BK=16 TM=8 TN=4, 256 threads.
// =====================================================================
template<bool NORM>
__global__ __launch_bounds__(256) void gemm_kernel(
    const float* __restrict__ A, const float* __restrict__ B, float* __restrict__ C,
    int M, int Nc, int K,
    const float* __restrict__ nscale, const float* __restrict__ nbias)
{
    constexpr int BM = 128, BN = 64, BK = 16, TM = 8, TN = 4;
    __shared__ float As[BK][BM + 4];
    __shared__ float Bs[BK][BN];

    const int t = threadIdx.x;
    const int row0 = blockIdx.x * BM;
    const int col0 = blockIdx.y * BN;
    const int trow = t >> 4;
    const int tcol = t & 15;

    float acc[TM][TN] = {};

    const int arow = t >> 2;
    const int akq = t & 3;

    for (int k0 = 0; k0 < K; k0 += BK) {
        #pragma unroll
        for (int half = 0; half < 2; ++half) {
            const int row = arow + half * 64;
            const int grow = row0 + row;
            float4 v = make_float4(0.f, 0.f, 0.f, 0.f);
            if (grow < M)
                v = *(const float4*)(A + (size_t)grow * K + k0 + akq * 4);
            if (NORM) {
                const float4 sc = *(const float4*)(nscale + k0 + akq * 4);
                const float4 bi = *(const float4*)(nbias + k0 + akq * 4);
                v.x = fmaxf(fmaf(v.x, sc.x, bi.x), 0.f);
                v.y = fmaxf(fmaf(v.y, sc.y, bi.y), 0.f);
                v.z = fmaxf(fmaf(v.z, sc.z, bi.z), 0.f);
                v.w = fmaxf(fmaf(v.w, sc.w, bi.w), 0.f);
            }
            As[akq * 4 + 0][row] = v.x;
            As[akq * 4 + 1][row] = v.y;
            As[akq * 4 + 2][row] = v.z;
            As[akq * 4 + 3][row] = v.w;
        }
        {
            const int krow = t >> 4, c4 = t & 15;
            const float4 v = *(const float4*)(B + (size_t)(k0 + krow) * Nc + col0 + c4 * 4);
            *(float4*)&Bs[krow][c4 * 4] = v;
        }
        __syncthreads();
        #pragma unroll
        for (int k = 0; k < BK; ++k) {
            const float4 a0 = *(const float4*)&As[k][trow * TM];
            const float4 a1 = *(const float4*)&As[k][trow * TM + 4];
            const float4 b4 = *(const float4*)&Bs[k][tcol * TN];
            const float a[8] = {a0.x, a0.y, a0.z, a0.w, a1.x, a1.y, a1.z, a1.w};
            const float b[4] = {b4.x, b4.y, b4.z, b4.w};
            #pragma unroll
            for (int i = 0; i < TM; ++i)
                #pragma unroll
                for (int j = 0; j < TN; ++j)
                    acc[i][j] = fmaf(a[i], b[j], acc[i][j]);
        }
        __syncthreads();
    }
    #pragma unroll
    for (int i = 0; i < TM; ++i) {
        const int grow = row0 + trow * TM + i;
        if (grow < M) {
            float4 v = make_float4(acc[i][0], acc[i][1], acc[i][2], acc[i][3]);
            *(float4*)(C + (size_t)grow * Nc + col0 + tcol * TN) = v;
        }
    }
}

// =====================================================================
// BatchNorm stats
// =====================================================================
__global__ __launch_bounds__(256) void bn_stats_kernel(
    const float* __restrict__ tin, float* __restrict__ sums, int M)
{
    __shared__ float sb[256], qb[256];
    const int col = threadIdx.x & 127;
    const int half = threadIdx.x >> 7;
    const int r0 = blockIdx.x * 128;
    float s = 0.f, q = 0.f;
    #pragma unroll 4
    for (int i = 0; i < 64; ++i) {
        const int r = r0 + i * 2 + half;
        if (r < M) {
            const float v = tin[(size_t)r * 128 + col];
            s += v; q += v * v;
        }
    }
    sb[threadIdx.x] = s; qb[threadIdx.x] = q;
    __syncthreads();
    if (threadIdx.x < 128) {
        s = sb[threadIdx.x] + sb[threadIdx.x + 128];
        q = qb[threadIdx.x] + qb[threadIdx.x + 128];
        unsafeAtomicAdd(&sums[col], s);
        unsafeAtomicAdd(&sums[128 + col], q);
    }
}

__global__ void bn_final_kernel(
    const float* __restrict__ sums, const float* __restrict__ g,
    const float* __restrict__ b, float* __restrict__ scale,
    float* __restrict__ bias, float invN)
{
    const int c = threadIdx.x;
    const float mu = sums[c] * invN;
    const float var = sums[128 + c] * invN - mu * mu;
    const float rs = rsqrtf(var + 1e-5f);
    const float sc = g[c] * rs;
    scale[c] = sc;
    bias[c] = b[c] - mu * sc;
}

// =====================================================================
// el/er: one wave per node
// =====================================================================
__global__ __launch_bounds__(256) void elr_kernel(
    const float* __restrict__ g, const float* __restrict__ al,
    const float* __restrict__ ar, float* __restrict__ el,
    float* __restrict__ er)
{
    const int wid = (blockIdx.x * 256 + threadIdx.x) >> 6;
    const int lane = threadIdx.x & 63;
    if (wid >= N_NODES) return;
    const int j = lane * 2;
    const float2 gv = *(const float2*)(g + (size_t)wid * 128 + j);
    const float2 av = *(const float2*)(al + j);
    const float2 bv = *(const float2*)(ar + j);
    float pl = gv.x * av.x + gv.y * av.y;
    float pr = gv.x * bv.x + gv.y * bv.y;
    #pragma unroll
    for (int m = 1; m < 8; m <<= 1) {
        pl += __shfl_xor(pl, m, 64);
        pr += __shfl_xor(pr, m, 64);
    }
    if ((lane & 7) == 0) {
        el[(size_t)wid * 8 + (lane >> 3)] = pl;
        er[(size_t)wid * 8 + (lane >> 3)] = pr;
    }
}

// =====================================================================
// Node-wise max of el and er (replaces per-edge max; leaky is monotonic
// so M = leaky(max el + max er) >= true edge max; softmax shift-invariant
// up to the 1e-16 guard -> ~1e-8 relative effect).
// =====================================================================
__global__ __launch_bounds__(256) void node_max_kernel(
    const float* __restrict__ el, const float* __restrict__ er,
    unsigned* __restrict__ menc)   // menc[0] <- max el, menc[1] <- max er
{
    const int n = N_NODES * H_HEADS;
    float ml = -3.0e38f, mr = -3.0e38f;
    for (int i = blockIdx.x * 256 + threadIdx.x; i < n; i += gridDim.x * 256) {
        ml = fmaxf(ml, el[i]);
        mr = fmaxf(mr, er[i]);
    }
    #pragma unroll
    for (int d = 1; d < 64; d <<= 1) {
        ml = fmaxf(ml, __shfl_xor(ml, d, 64));
        mr = fmaxf(mr, __shfl_xor(mr, d, 64));
    }
    __shared__ float sl[4], sr[4];
    const int wv = threadIdx.x >> 6;
    if ((threadIdx.x & 63) == 0) { sl[wv] = ml; sr[wv] = mr; }
    __syncthreads();
    if (threadIdx.x == 0) {
        ml = fmaxf(fmaxf(sl[0], sl[1]), fmaxf(sl[2], sl[3]));
        mr = fmaxf(fmaxf(sr[0], sr[1]), fmaxf(sr[2], sr[3]));
        atomicMax(&menc[0], encf(ml));
        atomicMax(&menc[1], encf(mr));
    }
}

__global__ void finalize_max_kernel(const unsigned* __restrict__ menc,
                                    float* __restrict__ Mfinal)
{
    const int r = threadIdx.x;
    if (r < R_REL) {
        const float s = decf(menc[r * 2]) + decf(menc[r * 2 + 1]);
        Mfinal[r] = s > 0.f ? s : 0.2f * s;
    }
}

// =====================================================================
// CSR build: histogram -> scan -> scatter (by target)
// =====================================================================
__global__ __launch_bounds__(256) void hist_kernel(
    const int* __restrict__ trg, int* __restrict__ deg)
{
    const int i = blockIdx.x * 256 + threadIdx.x;
    if (i < E_EDGES) atomicAdd(&deg[trg[i]], 1);
}

__global__ __launch_bounds__(1024) void scan_kernel(
    const int* __restrict__ deg, int* __restrict__ rowptr, int* __restrict__ cursor)
{
    __shared__ int psum[1024];
    const int t = threadIdx.x;
    const int CH = (N_NODES + 1023) / 1024;  // 49
    const int base = t * CH;
    int s = 0;
    for (int i = 0; i < CH; ++i) {
        const int idx = base + i;
        if (idx < N_NODES) s += deg[idx];
    }
    psum[t] = s;
    __syncthreads();
    for (int off = 1; off < 1024; off <<= 1) {
        const int v = (t >= off) ? psum[t - off] : 0;
        __syncthreads();
        psum[t] += v;
        __syncthreads();
    }
    int run = (t == 0) ? 0 : psum[t - 1];
    for (int i = 0; i < CH; ++i) {
        const int idx = base + i;
        if (idx < N_NODES) { rowptr[idx] = run; cursor[idx] = run; run += deg[idx]; }
    }
    if (t == 1023) rowptr[N_NODES] = run;
}

__global__ __launch_bounds__(256) void scatter_kernel(
    const int* __restrict__ src, const int* __restrict__ trg,
    int* __restrict__ cursor, int* __restrict__ srcs)
{
    const int i = blockIdx.x * 256 + threadIdx.x;
    if (i < E_EDGES) {
        const int pos = atomicAdd(&cursor[trg[i]], 1);
        srcs[pos] = src[i];
    }
}

// =====================================================================
// Aggregation: one wave per target node. Gather g[src] rows, weight by
// exp(leaky(el[s]+er[t],0.2)-M), accumulate num+den in registers, then
// fuse alpha-divide + leaky(0.01) + residual(+x) into the h write.
// =====================================================================
__global__ __launch_bounds__(256) void agg_kernel(
    const int* __restrict__ rowptr, const int* __restrict__ srcs,
    const float* __restrict__ g, const float* __restrict__ el,
    const float* __restrict__ er, const float* __restrict__ Mf,
    const float* __restrict__ x, float* __restrict__ hout, int rbase)
{
    const int wid = (blockIdx.x * 256 + threadIdx.x) >> 6;
    const int lane = threadIdx.x & 63;
    if (wid >= N_NODES) return;
    const int h = lane >> 3;
    const float M = *Mf;
    const float erv = er[(size_t)wid * 8 + h];
    const int p0 = rowptr[wid], p1 = rowptr[wid + 1];
    float a0 = 0.f, a1 = 0.f, den = 0.f;
    for (int base = p0; base < p1; base += 64) {
        int sv = 0;
        if (base + lane < p1) sv = srcs[base + lane];
        const int nn = min(64, p1 - base);
        for (int j = 0; j < nn; ++j) {
            const int s = __shfl(sv, j, 64);
            float sc = el[(size_t)s * 8 + h] + erv;
            sc = sc > 0.f ? sc : 0.2f * sc;
            const float ex = __expf(sc - M);
            const float2 gv = *(const float2*)(g + (size_t)s * 128 + lane * 2);
            a0 = fmaf(gv.x, ex, a0);
            a1 = fmaf(gv.y, ex, a1);
            den += ex;
        }
    }
    const float inv = 1.f / (den + 1e-16f);
    const size_t o = (size_t)wid * 384 + rbase + lane * 2;
    float v0 = a0 * inv, v1 = a1 * inv;
    v0 = v0 > 0.f ? v0 : 0.01f * v0;
    v1 = v1 > 0.f ? v1 : 0.01f * v1;
    hout[o]     = v0 + x[o];
    hout[o + 1] = v1 + x[o + 1];
}

// =====================================================================
extern "C" void kernel_launch(void* const* d_in, const int* in_sizes, int n_in,
                              void* d_out, int out_size, void* d_ws, size_t ws_size,
                              hipStream_t stream) {
    const float* inputs = (const float*)d_in[0];
    const int*   edges  = (const int*)d_in[1];
    const float* W_emb1 = (const float*)d_in[2];
    const float* W_emb2 = (const float*)d_in[3];
    const float* g_emb  = (const float*)d_in[4];
    const float* b_emb  = (const float*)d_in[5];
    const float* Wg     = (const float*)d_in[6];
    const float* al     = (const float*)d_in[7];
    const float* ar     = (const float*)d_in[8];
    const float* W_d1   = (const float*)d_in[9];
    const float* W_d2   = (const float*)d_in[10];
    const float* g_d    = (const float*)d_in[11];
    const float* b_d    = (const float*)d_in[12];
    float* out = (float*)d_out;

    // ---- workspace layout ----
    float* w = (float*)d_ws;
    float* x     = w; w += (size_t)N_NODES * D_F;
    float* h     = w; w += (size_t)N_NODES * D_F;
    float* t1a   = w; w += (size_t)N_NODES * HID_F;
    float* t1b   = w; w += (size_t)N_NODES * HID_F;
    float* t1c   = w; w += (size_t)N_NODES * HID_F;
    float* el    = w; w += (size_t)R_REL * N_NODES * H_HEADS;
    float* er    = w; w += (size_t)R_REL * N_NODES * H_HEADS;
    float* sums  = w; w += 256;
    float* scale = w; w += 128;
    float* bias  = w; w += 128;
    unsigned* Menc = (unsigned*)w; w += 8;     // [r][2] encoded node maxes
    float* Mfinal  = w; w += 4;                // per-relation final shift
    int* rowptr = (int*)w; w += (size_t)R_REL * (N_NODES + 1);
    int* srcs   = (int*)w; w += (size_t)R_REL * E_EDGES;
    int* deg    = (int*)w; w += N_NODES;
    int* cursor = (int*)w; w += N_NODES;
    float* t1s[3] = {t1a, t1b, t1c};

    auto gemm = [&](const float* A, const float* B, float* C, int M, int Nc, int K,
                    const float* sc, const float* bi) {
        dim3 grid((M + 127) / 128, Nc / 64);
        if (sc)
            gemm_kernel<true><<<grid, 256, 0, stream>>>(A, B, C, M, Nc, K, sc, bi);
        else
            gemm_kernel<false><<<grid, 256, 0, stream>>>(A, B, C, M, Nc, K, nullptr, nullptr);
    };

    // ---- Build CSR (by target) for each relation ----
    for (int r = 0; r < R_REL; ++r) {
        const int* srcp = edges + (size_t)r * 2 * E_EDGES;
        const int* trgp = srcp + E_EDGES;
        hipMemsetAsync(deg, 0, N_NODES * sizeof(int), stream);
        hist_kernel<<<(E_EDGES + 255) / 256, 256, 0, stream>>>(trgp, deg);
        scan_kernel<<<1, 1024, 0, stream>>>(deg, rowptr + (size_t)r * (N_NODES + 1), cursor);
        scatter_kernel<<<(E_EDGES + 255) / 256, 256, 0, stream>>>(
            srcp, trgp, cursor, srcs + (size_t)r * E_EDGES);
    }

    // ---- Embedding MLP: x = relu(BN(inputs@W_emb1)) @ W_emb2 ----
    gemm(inputs, W_emb1, t1a, N_NODES, HID_F, IN_F, nullptr, nullptr);
    hipMemsetAsync(sums, 0, 256 * sizeof(float), stream);
    bn_stats_kernel<<<(N_NODES + 127) / 128, 256, 0, stream>>>(t1a, sums, N_NODES);
    bn_final_kernel<<<1, 128, 0, stream>>>(sums, g_emb, b_emb, scale, bias, 1.0f / N_NODES);
    gemm(t1a, W_emb2, x, N_NODES, D_F, HID_F, scale, bias);
    hipMemcpyAsync(h, x, (size_t)N_NODES * D_F * sizeof(float),
                   hipMemcpyDeviceToDevice, stream);

    // ---- GAT layers ----
    for (int l = 0; l < L_LAYERS; ++l) {
        hipMemsetAsync(Menc, 0, 2 * R_REL * sizeof(unsigned), stream);
        for (int r = 0; r < R_REL; ++r) {
            const int lr = l * R_REL + r;
            gemm(h, Wg + (size_t)lr * D_F * (H_HEADS * O_PER), t1s[r], N_NODES,
                 H_HEADS * O_PER, D_F, nullptr, nullptr);
            elr_kernel<<<(N_NODES + 3) / 4, 256, 0, stream>>>(
                t1s[r], al + lr * (H_HEADS * O_PER), ar + lr * (H_HEADS * O_PER),
                el + (size_t)r * N_NODES * H_HEADS, er + (size_t)r * N_NODES * H_HEADS);
            node_max_kernel<<<128, 256, 0, stream>>>(
                el + (size_t)r * N_NODES * H_HEADS,
                er + (size_t)r * N_NODES * H_HEADS, Menc + r * 2);
        }
        finalize_max_kernel<<<1, 64, 0, stream>>>(Menc, Mfinal);
        // h is only WRITTEN here (inputs are t1/el/er/x), so in-place is safe
        for (int r = 0; r < R_REL; ++r) {
            agg_kernel<<<(N_NODES * 64 + 255) / 256, 256, 0, stream>>>(
                rowptr + (size_t)r * (N_NODES + 1), srcs + (size_t)r * E_EDGES,
                t1s[r], el + (size_t)r * N_NODES * H_HEADS,
                er + (size_t)r * N_NODES * H_HEADS, Mfinal + r, x, h, r * 128);
        }
    }

    // ---- Decoder MLP: out = relu(BN(h@W_d1)) @ W_d2 ----
    gemm(h, W_d1, t1a, N_NODES, HID_F, D_F, nullptr, nullptr);
    hipMemsetAsync(sums, 0, 256 * sizeof(float), stream);
    bn_stats_kernel<<<(N_NODES + 127) / 128, 256, 0, stream>>>(t1a, sums, N_NODES);
    bn_final_kernel<<<1, 128, 0, stream>>>(sums, g_d, b_d, scale, bias, 1.0f / N_NODES);
    gemm(t1a, W_d2, out, N_NODES, OUT_F, HID_F, scale, bias);
}

// Round 5
// 1852.178 us; speedup vs baseline: 6.3859x; 1.5798x over previous
//
#include <hip/hip_runtime.h>
#include <hip/hip_bf16.h>
#include <cstdint>

#define N_NODES 50000
#define E_EDGES 800000
#define R_REL   3
#define IN_F    128
#define HID_F   128
#define D_F     384
#define H_HEADS 8
#define O_PER   16
#define OUT_F   64
#define L_LAYERS 4
#define NB_SCAN 196   // ceil(50000/256)
#define M_PAD   50048 // 391*128

typedef __attribute__((ext_vector_type(8))) short short8;
typedef __attribute__((ext_vector_type(8))) unsigned short ushort8;
typedef __attribute__((ext_vector_type(4))) float f32x4;

// ---- float atomicMax encoding (monotonic uint mapping) ----
__device__ __forceinline__ unsigned encf(float f) {
    unsigned u = __float_as_uint(f);
    return (u & 0x80000000u) ? ~u : (u | 0x80000000u);
}
__device__ __forceinline__ float decf(unsigned u) {
    return __uint_as_float((u & 0x80000000u) ? (u ^ 0x80000000u) : ~u);
}

__device__ __forceinline__ void split2(float v, unsigned short& hi, unsigned short& lo) {
    const unsigned u = __float_as_uint(v);
    hi = (unsigned short)(u >> 16);
    const float r = v - __uint_as_float(u & 0xFFFF0000u);
    lo = (unsigned short)(__float_as_uint(r) >> 16);
}

// =====================================================================
// Split-bf16 MFMA GEMM: C[M,Nc] = A[M,K] @ B[K,Nc]
// A: fp32, converted to hi/lo bf16 during LDS staging (NORM fuses BN+ReLU).
// B: pre-split bf16 hi/lo, layout [Nc][K] (n-major).
// Block 128x128, 4 waves (2x2) of 64x64, BK=64, mfma_f32_16x16x32_bf16.
// acc = Ah*Bh + Ah*Bl + Al*Bh  (~fp32 precision).
// LDS blocks of 8 elems XOR-swizzled: stored blk = blk_glob ^ (row&7).
// =====================================================================
template<bool NORM>
__global__ __launch_bounds__(256) void mfma_gemm(
    const float* __restrict__ A, const unsigned short* __restrict__ Bhi,
    const unsigned short* __restrict__ Blo, float* __restrict__ C,
    int M, int K, int Nc,
    const float* __restrict__ nscale, const float* __restrict__ nbias)
{
    __shared__ __align__(16) unsigned short sAh[128 * 64];
    __shared__ __align__(16) unsigned short sAl[128 * 64];
    __shared__ __align__(16) unsigned short sBh[128 * 64];
    __shared__ __align__(16) unsigned short sBl[128 * 64];

    const int t = threadIdx.x;
    const int lane = t & 63;
    const int w = t >> 6;
    const int wm = (w >> 1) * 64;
    const int wn = (w & 1) * 64;
    const int row0 = blockIdx.x * 128;
    const int col0 = blockIdx.y * 128;
    const unsigned short* bh = Bhi + (size_t)col0 * K;
    const unsigned short* bl = Blo + (size_t)col0 * K;

    f32x4 acc[4][4] = {};

    for (int k0 = 0; k0 < K; k0 += 64) {
        // ---- stage A: fp32 -> hi/lo bf16 (8 elems = one 16B LDS block per chunk)
        #pragma unroll
        for (int c = 0; c < 4; ++c) {
            const int lb = c * 256 + t;        // LDS block index 0..1023
            const int arow = lb >> 3;          // 0..127
            const int bkg = (lb & 7) ^ (arow & 7);
            const int grow = row0 + arow;
            float4 v0 = make_float4(0.f, 0.f, 0.f, 0.f), v1 = v0;
            if (grow < M) {
                const float* ap = A + (size_t)grow * K + k0 + bkg * 8;
                v0 = *(const float4*)ap;
                v1 = *(const float4*)(ap + 4);
            }
            if (NORM) {
                const float4 s0 = *(const float4*)(nscale + k0 + bkg * 8);
                const float4 s1 = *(const float4*)(nscale + k0 + bkg * 8 + 4);
                const float4 b0 = *(const float4*)(nbias + k0 + bkg * 8);
                const float4 b1 = *(const float4*)(nbias + k0 + bkg * 8 + 4);
                v0.x = fmaxf(fmaf(v0.x, s0.x, b0.x), 0.f);
                v0.y = fmaxf(fmaf(v0.y, s0.y, b0.y), 0.f);
                v0.z = fmaxf(fmaf(v0.z, s0.z, b0.z), 0.f);
                v0.w = fmaxf(fmaf(v0.w, s0.w, b0.w), 0.f);
                v1.x = fmaxf(fmaf(v1.x, s1.x, b1.x), 0.f);
                v1.y = fmaxf(fmaf(v1.y, s1.y, b1.y), 0.f);
                v1.z = fmaxf(fmaf(v1.z, s1.z, b1.z), 0.f);
                v1.w = fmaxf(fmaf(v1.w, s1.w, b1.w), 0.f);
            }
            ushort8 vh, vl;
            unsigned short h_, l_;
            split2(v0.x, h_, l_); vh[0] = h_; vl[0] = l_;
            split2(v0.y, h_, l_); vh[1] = h_; vl[1] = l_;
            split2(v0.z, h_, l_); vh[2] = h_; vl[2] = l_;
            split2(v0.w, h_, l_); vh[3] = h_; vl[3] = l_;
            split2(v1.x, h_, l_); vh[4] = h_; vl[4] = l_;
            split2(v1.y, h_, l_); vh[5] = h_; vl[5] = l_;
            split2(v1.z, h_, l_); vh[6] = h_; vl[6] = l_;
            split2(v1.w, h_, l_); vh[7] = h_; vl[7] = l_;
            *(ushort8*)&sAh[lb * 8] = vh;
            *(ushort8*)&sAl[lb * 8] = vl;
        }
        // ---- stage B: bf16 hi/lo straight copy
        #pragma unroll
        for (int c = 0; c < 4; ++c) {
            const int lb = c * 256 + t;
            const int nrow = lb >> 3;
            const int bkg = (lb & 7) ^ (nrow & 7);
            const size_t go = (size_t)nrow * K + k0 + bkg * 8;
            *(ushort8*)&sBh[lb * 8] = *(const ushort8*)(bh + go);
            *(ushort8*)&sBl[lb * 8] = *(const ushort8*)(bl + go);
        }
        __syncthreads();
        // ---- compute: 2 sub-steps of k=32
        const int g = lane >> 4;
        const int l15 = lane & 15;
        #pragma unroll
        for (int s = 0; s < 2; ++s) {
            short8 ah[4], al_[4], bhf[4], blf[4];
            #pragma unroll
            for (int mf = 0; mf < 4; ++mf) {
                const int rm = wm + mf * 16 + l15;
                const int idx = rm * 64 + ((s * 4 + g) ^ (rm & 7)) * 8;
                ah[mf]  = *(const short8*)&sAh[idx];
                al_[mf] = *(const short8*)&sAl[idx];
            }
            #pragma unroll
            for (int nf = 0; nf < 4; ++nf) {
                const int rn = wn + nf * 16 + l15;
                const int idx = rn * 64 + ((s * 4 + g) ^ (rn & 7)) * 8;
                bhf[nf] = *(const short8*)&sBh[idx];
                blf[nf] = *(const short8*)&sBl[idx];
            }
            #pragma unroll
            for (int mf = 0; mf < 4; ++mf)
                #pragma unroll
                for (int nf = 0; nf < 4; ++nf) {
                    acc[mf][nf] = __builtin_amdgcn_mfma_f32_16x16x32_bf16(
                        ah[mf], bhf[nf], acc[mf][nf], 0, 0, 0);
                    acc[mf][nf] = __builtin_amdgcn_mfma_f32_16x16x32_bf16(
                        ah[mf], blf[nf], acc[mf][nf], 0, 0, 0);
                    acc[mf][nf] = __builtin_amdgcn_mfma_f32_16x16x32_bf16(
                        al_[mf], bhf[nf], acc[mf][nf], 0, 0, 0);
                }
        }
        __syncthreads();
    }
    // ---- epilogue: C/D layout col=lane&15, row=(lane>>4)*4+reg
    #pragma unroll
    for (int mf = 0; mf < 4; ++mf)
        #pragma unroll
        for (int j = 0; j < 4; ++j) {
            const int row = row0 + wm + mf * 16 + (lane >> 4) * 4 + j;
            if (row < M) {
                #pragma unroll
                for (int nf = 0; nf < 4; ++nf)
                    C[(size_t)row * Nc + col0 + wn + nf * 16 + (lane & 15)] = acc[mf][nf][j];
            }
        }
}

// =====================================================================
// Weight split+transpose: in W[K0][N0] (k-major), out hi/lo [N0][K0]
// per matrix, nmat matrices.
// =====================================================================
__global__ __launch_bounds__(256) void wsplit_kernel(
    const float* __restrict__ W, unsigned short* __restrict__ hi,
    unsigned short* __restrict__ lo, int K0, int N0, int total)
{
    const int t = blockIdx.x * 256 + threadIdx.x;
    if (t >= total) return;
    const int per = K0 * N0;
    const int m = t / per;
    const int rem = t - m * per;
    const int n = rem / K0;
    const int k = rem - n * K0;
    const float v = W[(size_t)m * per + (size_t)k * N0 + n];
    unsigned short h_, l_;
    split2(v, h_, l_);
    hi[t] = h_; lo[t] = l_;
}

// =====================================================================
// fp32 VALU GEMM (kept for dec2 only): BM=128 BN=64 BK=16
// =====================================================================
template<bool NORM>
__global__ __launch_bounds__(256) void gemm_kernel(
    const float* __restrict__ A, const float* __restrict__ B, float* __restrict__ C,
    int M, int Nc, int K,
    const float* __restrict__ nscale, const float* __restrict__ nbias)
{
    constexpr int BM = 128, BN = 64, BK = 16, TM = 8, TN = 4;
    __shared__ float As[BK][BM + 4];
    __shared__ float Bs[BK][BN];
    const int t = threadIdx.x;
    const int row0 = blockIdx.x * BM;
    const int col0 = blockIdx.y * BN;
    const int trow = t >> 4;
    const int tcol = t & 15;
    float acc[TM][TN] = {};
    const int arow = t >> 2;
    const int akq = t & 3;
    for (int k0 = 0; k0 < K; k0 += BK) {
        #pragma unroll
        for (int half = 0; half < 2; ++half) {
            const int row = arow + half * 64;
            const int grow = row0 + row;
            float4 v = make_float4(0.f, 0.f, 0.f, 0.f);
            if (grow < M)
                v = *(const float4*)(A + (size_t)grow * K + k0 + akq * 4);
            if (NORM) {
                const float4 sc = *(const float4*)(nscale + k0 + akq * 4);
                const float4 bi = *(const float4*)(nbias + k0 + akq * 4);
                v.x = fmaxf(fmaf(v.x, sc.x, bi.x), 0.f);
                v.y = fmaxf(fmaf(v.y, sc.y, bi.y), 0.f);
                v.z = fmaxf(fmaf(v.z, sc.z, bi.z), 0.f);
                v.w = fmaxf(fmaf(v.w, sc.w, bi.w), 0.f);
            }
            As[akq * 4 + 0][row] = v.x;
            As[akq * 4 + 1][row] = v.y;
            As[akq * 4 + 2][row] = v.z;
            As[akq * 4 + 3][row] = v.w;
        }
        {
            const int krow = t >> 4, c4 = t & 15;
            const float4 v = *(const float4*)(B + (size_t)(k0 + krow) * Nc + col0 + c4 * 4);
            *(float4*)&Bs[krow][c4 * 4] = v;
        }
        __syncthreads();
        #pragma unroll
        for (int k = 0; k < BK; ++k) {
            const float4 a0 = *(const float4*)&As[k][trow * TM];
            const float4 a1 = *(const float4*)&As[k][trow * TM + 4];
            const float4 b4 = *(const float4*)&Bs[k][tcol * TN];
            const float a[8] = {a0.x, a0.y, a0.z, a0.w, a1.x, a1.y, a1.z, a1.w};
            const float b[4] = {b4.x, b4.y, b4.z, b4.w};
            #pragma unroll
            for (int i = 0; i < TM; ++i)
                #pragma unroll
                for (int j = 0; j < TN; ++j)
                    acc[i][j] = fmaf(a[i], b[j], acc[i][j]);
        }
        __syncthreads();
    }
    #pragma unroll
    for (int i = 0; i < TM; ++i) {
        const int grow = row0 + trow * TM + i;
        if (grow < M) {
            float4 v = make_float4(acc[i][0], acc[i][1], acc[i][2], acc[i][3]);
            *(float4*)(C + (size_t)grow * Nc + col0 + tcol * TN) = v;
        }
    }
}

// =====================================================================
// BatchNorm stats
// =====================================================================
__global__ __launch_bounds__(256) void bn_stats_kernel(
    const float* __restrict__ tin, float* __restrict__ sums, int M)
{
    __shared__ float sb[256], qb[256];
    const int col = threadIdx.x & 127;
    const int half = threadIdx.x >> 7;
    const int r0 = blockIdx.x * 128;
    float s = 0.f, q = 0.f;
    #pragma unroll 4
    for (int i = 0; i < 64; ++i) {
        const int r = r0 + i * 2 + half;
        if (r < M) {
            const float v = tin[(size_t)r * 128 + col];
            s += v; q += v * v;
        }
    }
    sb[threadIdx.x] = s; qb[threadIdx.x] = q;
    __syncthreads();
    if (threadIdx.x < 128) {
        s = sb[threadIdx.x] + sb[threadIdx.x + 128];
        q = qb[threadIdx.x] + qb[threadIdx.x + 128];
        unsafeAtomicAdd(&sums[col], s);
        unsafeAtomicAdd(&sums[128 + col], q);
    }
}

__global__ void bn_final_kernel(
    const float* __restrict__ sums, const float* __restrict__ g,
    const float* __restrict__ b, float* __restrict__ scale,
    float* __restrict__ bias, float invN)
{
    const int c = threadIdx.x;
    const float mu = sums[c] * invN;
    const float var = sums[128 + c] * invN - mu * mu;
    const float rs = rsqrtf(var + 1e-5f);
    const float sc = g[c] * rs;
    scale[c] = sc;
    bias[c] = b[c] - mu * sc;
}

// =====================================================================
// el/er: one wave per node; g row lives in tcat [N][384] at col rbase
// =====================================================================
__global__ __launch_bounds__(256) void elr_kernel(
    const float* __restrict__ g, int rbase, const float* __restrict__ al,
    const float* __restrict__ ar, float* __restrict__ el,
    float* __restrict__ er)
{
    const int wid = (blockIdx.x * 256 + threadIdx.x) >> 6;
    const int lane = threadIdx.x & 63;
    if (wid >= N_NODES) return;
    const int j = lane * 2;
    const float2 gv = *(const float2*)(g + (size_t)wid * 384 + rbase + j);
    const float2 av = *(const float2*)(al + j);
    const float2 bv = *(const float2*)(ar + j);
    float pl = gv.x * av.x + gv.y * av.y;
    float pr = gv.x * bv.x + gv.y * bv.y;
    #pragma unroll
    for (int m = 1; m < 8; m <<= 1) {
        pl += __shfl_xor(pl, m, 64);
        pr += __shfl_xor(pr, m, 64);
    }
    if ((lane & 7) == 0) {
        el[(size_t)wid * 8 + (lane >> 3)] = pl;
        er[(size_t)wid * 8 + (lane >> 3)] = pr;
    }
}

// =====================================================================
// Node-wise max of el and er
// =====================================================================
__global__ __launch_bounds__(256) void node_max_kernel(
    const float* __restrict__ el, const float* __restrict__ er,
    unsigned* __restrict__ menc)
{
    const int n = N_NODES * H_HEADS;
    float ml = -3.0e38f, mr = -3.0e38f;
    for (int i = blockIdx.x * 256 + threadIdx.x; i < n; i += gridDim.x * 256) {
        ml = fmaxf(ml, el[i]);
        mr = fmaxf(mr, er[i]);
    }
    #pragma unroll
    for (int d = 1; d < 64; d <<= 1) {
        ml = fmaxf(ml, __shfl_xor(ml, d, 64));
        mr = fmaxf(mr, __shfl_xor(mr, d, 64));
    }
    __shared__ float sl[4], sr[4];
    const int wv = threadIdx.x >> 6;
    if ((threadIdx.x & 63) == 0) { sl[wv] = ml; sr[wv] = mr; }
    __syncthreads();
    if (threadIdx.x == 0) {
        ml = fmaxf(fmaxf(sl[0], sl[1]), fmaxf(sl[2], sl[3]));
        mr = fmaxf(fmaxf(sr[0], sr[1]), fmaxf(sr[2], sr[3]));
        atomicMax(&menc[0], encf(ml));
        atomicMax(&menc[1], encf(mr));
    }
}

__global__ void finalize_max_kernel(const unsigned* __restrict__ menc,
                                    float* __restrict__ Mfinal)
{
    const int r = threadIdx.x;
    if (r < R_REL) {
        const float s = decf(menc[r * 2]) + decf(menc[r * 2 + 1]);
        Mfinal[r] = s > 0.f ? s : 0.2f * s;
    }
}

// =====================================================================
// CSR build (all relations fused): hist -> 3-phase scan -> scatter
// =====================================================================
__global__ __launch_bounds__(256) void hist_all_kernel(
    const int* __restrict__ edges, int* __restrict__ deg)
{
    const int r = blockIdx.y;
    const int i = blockIdx.x * 256 + threadIdx.x;
    if (i < E_EDGES)
        atomicAdd(&deg[r * N_NODES + edges[(size_t)r * 2 * E_EDGES + E_EDGES + i]], 1);
}

__global__ __launch_bounds__(256) void scan1_kernel(
    const int* __restrict__ deg, int* __restrict__ bsum)
{
    const int r = blockIdx.y;
    const int i = blockIdx.x * 256 + threadIdx.x;
    __shared__ int sh[256];
    sh[threadIdx.x] = (i < N_NODES) ? deg[r * N_NODES + i] : 0;
    __syncthreads();
    for (int off = 128; off > 0; off >>= 1) {
        if (threadIdx.x < off) sh[threadIdx.x] += sh[threadIdx.x + off];
        __syncthreads();
    }
    if (threadIdx.x == 0) bsum[r * NB_SCAN + blockIdx.x] = sh[0];
}

__global__ __launch_bounds__(256) void scan2_kernel(int* __restrict__ bsum)
{
    const int r = blockIdx.x;
    const int t = threadIdx.x;
    __shared__ int sh[256];
    const int v = (t < NB_SCAN) ? bsum[r * NB_SCAN + t] : 0;
    sh[t] = v;
    __syncthreads();
    for (int off = 1; off < 256; off <<= 1) {
        const int u = (t >= off) ? sh[t - off] : 0;
        __syncthreads();
        sh[t] += u;
        __syncthreads();
    }
    if (t < NB_SCAN) bsum[r * NB_SCAN + t] = sh[t] - v;  // exclusive
}

__global__ __launch_bounds__(256) void scan3_kernel(
    const int* __restrict__ deg, const int* __restrict__ bsum,
    int* __restrict__ rowptr, int* __restrict__ cursor)
{
    const int r = blockIdx.y;
    const int i = blockIdx.x * 256 + threadIdx.x;
    const int t = threadIdx.x;
    __shared__ int sh[256];
    const int v = (i < N_NODES) ? deg[r * N_NODES + i] : 0;
    sh[t] = v;
    __syncthreads();
    for (int off = 1; off < 256; off <<= 1) {
        const int u = (t >= off) ? sh[t - off] : 0;
        __syncthreads();
        sh[t] += u;
        __syncthreads();
    }
    const int excl = sh[t] - v + bsum[r * NB_SCAN + blockIdx.x];
    if (i < N_NODES) {
        rowptr[(size_t)r * (N_NODES + 1) + i] = excl;
        cursor[r * N_NODES + i] = excl;
        if (i == N_NODES - 1) rowptr[(size_t)r * (N_NODES + 1) + N_NODES] = excl + v;
    }
}

__global__ __launch_bounds__(256) void scatter_all_kernel(
    const int* __restrict__ edges, int* __restrict__ cursor, int* __restrict__ srcs)
{
    const int r = blockIdx.y;
    const int i = blockIdx.x * 256 + threadIdx.x;
    if (i < E_EDGES) {
        const int s  = edges[(size_t)r * 2 * E_EDGES + i];
        const int tg = edges[(size_t)r * 2 * E_EDGES + E_EDGES + i];
        const int pos = atomicAdd(&cursor[r * N_NODES + tg], 1);
        srcs[(size_t)r * E_EDGES + pos] = s;
    }
}

// =====================================================================
// Aggregation: one wave per target node (gather + register accumulate),
// fused alpha-divide + leaky(0.01) + residual into h write.
// =====================================================================
__global__ __launch_bounds__(256) void agg_kernel(
    const int* __restrict__ rowptr, const int* __restrict__ srcs,
    const float* __restrict__ g, int rbase, const float* __restrict__ el,
    const float* __restrict__ er, const float* __restrict__ Mf,
    const float* __restrict__ x, float* __restrict__ hout)
{
    const int wid = (blockIdx.x * 256 + threadIdx.x) >> 6;
    const int lane = threadIdx.x & 63;
    if (wid >= N_NODES) return;
    const int h = lane >> 3;
    const float M = *Mf;
    const float erv = er[(size_t)wid * 8 + h];
    const int p0 = rowptr[wid], p1 = rowptr[wid + 1];
    float a0 = 0.f, a1 = 0.f, den = 0.f;
    for (int base = p0; base < p1; base += 64) {
        int sv = 0;
        if (base + lane < p1) sv = srcs[base + lane];
        const int nn = min(64, p1 - base);
        for (int j = 0; j < nn; ++j) {
            const int s = __shfl(sv, j, 64);
            float sc = el[(size_t)s * 8 + h] + erv;
            sc = sc > 0.f ? sc : 0.2f * sc;
            const float ex = __expf(sc - M);
            const float2 gv = *(const float2*)(g + (size_t)s * 384 + rbase + lane * 2);
            a0 = fmaf(gv.x, ex, a0);
            a1 = fmaf(gv.y, ex, a1);
            den += ex;
        }
    }
    const float inv = 1.f / (den + 1e-16f);
    const size_t o = (size_t)wid * 384 + rbase + lane * 2;
    float v0 = a0 * inv, v1 = a1 * inv;
    v0 = v0 > 0.f ? v0 : 0.01f * v0;
    v1 = v1 > 0.f ? v1 : 0.01f * v1;
    hout[o]     = v0 + x[o];
    hout[o + 1] = v1 + x[o + 1];
}

// =====================================================================
extern "C" void kernel_launch(void* const* d_in, const int* in_sizes, int n_in,
                              void* d_out, int out_size, void* d_ws, size_t ws_size,
                              hipStream_t stream) {
    const float* inputs = (const float*)d_in[0];
    const int*   edges  = (const int*)d_in[1];
    const float* W_emb1 = (const float*)d_in[2];
    const float* W_emb2 = (const float*)d_in[3];
    const float* g_emb  = (const float*)d_in[4];
    const float* b_emb  = (const float*)d_in[5];
    const float* Wg     = (const float*)d_in[6];
    const float* al     = (const float*)d_in[7];
    const float* ar     = (const float*)d_in[8];
    const float* W_d1   = (const float*)d_in[9];
    const float* W_d2   = (const float*)d_in[10];
    const float* g_d    = (const float*)d_in[11];
    const float* b_d    = (const float*)d_in[12];
    float* out = (float*)d_out;

    // ---- workspace carve (aligned). Budget: ws_size = 256 MiB.
    // Total carved below ~= 253.1 MB (241 MiB). Aliases:
    //   t1  -> head of tcat   (t1 only used in MLP phases, tcat only in GAT loop)
    //   deg/cursor/bsum -> el/er region (CSR build finishes before el/er written)
    char* base = (char*)d_ws;
    size_t off = 0;
    auto carve = [&](size_t bytes) {
        void* p = base + off;
        off = (off + bytes + 255) & ~(size_t)255;
        return p;
    };
    float* x    = (float*)carve((size_t)N_NODES * D_F * 4);     // 76.8 MB
    float* h    = (float*)carve((size_t)N_NODES * D_F * 4);     // 76.8 MB
    float* tcat = (float*)carve((size_t)N_NODES * D_F * 4);     // 76.8 MB
    float* t1   = tcat;                                          // ALIAS (25.6 MB head)
    float* el   = (float*)carve((size_t)R_REL * N_NODES * H_HEADS * 4);  // 4.8 MB
    float* er   = (float*)carve((size_t)R_REL * N_NODES * H_HEADS * 4);  // 4.8 MB
    int* deg    = (int*)el;                                      // ALIAS (0.6 MB)
    int* cursor = (int*)er;                                      // ALIAS (0.6 MB)
    int* bsum   = (int*)er + R_REL * N_NODES;                    // ALIAS (2.4 KB, after cursor)
    unsigned short* wg_hi  = (unsigned short*)carve((size_t)12 * 384 * 128 * 2);
    unsigned short* wg_lo  = (unsigned short*)carve((size_t)12 * 384 * 128 * 2);
    unsigned short* we1_hi = (unsigned short*)carve((size_t)128 * 128 * 2);
    unsigned short* we1_lo = (unsigned short*)carve((size_t)128 * 128 * 2);
    unsigned short* we2_hi = (unsigned short*)carve((size_t)128 * 384 * 2);
    unsigned short* we2_lo = (unsigned short*)carve((size_t)128 * 384 * 2);
    unsigned short* wd1_hi = (unsigned short*)carve((size_t)384 * 128 * 2);
    unsigned short* wd1_lo = (unsigned short*)carve((size_t)384 * 128 * 2);
    float* sums  = (float*)carve(256 * 4);
    float* scale = (float*)carve(128 * 4);
    float* bias  = (float*)carve(128 * 4);
    unsigned* Menc = (unsigned*)carve(8 * 4);
    float* Mfinal  = (float*)carve(4 * 4);
    int* rowptr = (int*)carve((size_t)R_REL * (N_NODES + 1) * 4);  // 0.6 MB
    int* srcs   = (int*)carve((size_t)R_REL * E_EDGES * 4);        // 9.6 MB

    auto mgemm = [&](const float* A, const unsigned short* Bh, const unsigned short* Bl,
                     float* C, int M, int K, int Nc, const float* sc, const float* bi) {
        dim3 grid(M_PAD / 128, Nc / 128);
        if (sc)
            mfma_gemm<true><<<grid, 256, 0, stream>>>(A, Bh, Bl, C, M, K, Nc, sc, bi);
        else
            mfma_gemm<false><<<grid, 256, 0, stream>>>(A, Bh, Bl, C, M, K, Nc, nullptr, nullptr);
    };

    // ---- weight splits (hi/lo bf16, transposed to [Nc][K]) ----
    {
        int tot = 12 * 384 * 128;
        wsplit_kernel<<<(tot + 255) / 256, 256, 0, stream>>>(Wg, wg_hi, wg_lo, 384, 128, tot);
        tot = 128 * 128;
        wsplit_kernel<<<(tot + 255) / 256, 256, 0, stream>>>(W_emb1, we1_hi, we1_lo, 128, 128, tot);
        tot = 128 * 384;
        wsplit_kernel<<<(tot + 255) / 256, 256, 0, stream>>>(W_emb2, we2_hi, we2_lo, 128, 384, tot);
        tot = 384 * 128;
        wsplit_kernel<<<(tot + 255) / 256, 256, 0, stream>>>(W_d1, wd1_hi, wd1_lo, 384, 128, tot);
    }

    // ---- CSR build (all relations) — uses deg/cursor/bsum aliased into el/er,
    //      which are not written until the GAT loop.
    hipMemsetAsync(deg, 0, (size_t)R_REL * N_NODES * 4, stream);
    {
        dim3 ge((E_EDGES + 255) / 256, R_REL);
        dim3 gn(NB_SCAN, R_REL);
        hist_all_kernel<<<ge, 256, 0, stream>>>(edges, deg);
        scan1_kernel<<<gn, 256, 0, stream>>>(deg, bsum);
        scan2_kernel<<<R_REL, 256, 0, stream>>>(bsum);
        scan3_kernel<<<gn, 256, 0, stream>>>(deg, bsum, rowptr, cursor);
        scatter_all_kernel<<<ge, 256, 0, stream>>>(edges, cursor, srcs);
    }

    // ---- Embedding MLP: x = relu(BN(inputs@W_emb1)) @ W_emb2 ----
    mgemm(inputs, we1_hi, we1_lo, t1, N_NODES, IN_F, HID_F, nullptr, nullptr);
    hipMemsetAsync(sums, 0, 256 * 4, stream);
    bn_stats_kernel<<<(N_NODES + 127) / 128, 256, 0, stream>>>(t1, sums, N_NODES);
    bn_final_kernel<<<1, 128, 0, stream>>>(sums, g_emb, b_emb, scale, bias, 1.0f / N_NODES);
    mgemm(t1, we2_hi, we2_lo, x, N_NODES, HID_F, D_F, scale, bias);
    hipMemcpyAsync(h, x, (size_t)N_NODES * D_F * 4, hipMemcpyDeviceToDevice, stream);

    // ---- GAT layers ----
    for (int l = 0; l < L_LAYERS; ++l) {
        // fused 3-relation GEMM: tcat[N,384] = h @ [Wg(l,0)|Wg(l,1)|Wg(l,2)]
        mgemm(h, wg_hi + (size_t)l * 384 * 384, wg_lo + (size_t)l * 384 * 384,
              tcat, N_NODES, D_F, 3 * HID_F, nullptr, nullptr);
        hipMemsetAsync(Menc, 0, 2 * R_REL * 4, stream);
        for (int r = 0; r < R_REL; ++r) {
            const int lr = l * R_REL + r;
            elr_kernel<<<(N_NODES + 3) / 4, 256, 0, stream>>>(
                tcat, r * 128, al + lr * 128, ar + lr * 128,
                el + (size_t)r * N_NODES * 8, er + (size_t)r * N_NODES * 8);
            node_max_kernel<<<128, 256, 0, stream>>>(
                el + (size_t)r * N_NODES * 8, er + (size_t)r * N_NODES * 8, Menc + r * 2);
        }
        finalize_max_kernel<<<1, 64, 0, stream>>>(Menc, Mfinal);
        for (int r = 0; r < R_REL; ++r) {
            agg_kernel<<<(N_NODES * 64 + 255) / 256, 256, 0, stream>>>(
                rowptr + (size_t)r * (N_NODES + 1), srcs + (size_t)r * E_EDGES,
                tcat, r * 128, el + (size_t)r * N_NODES * 8,
                er + (size_t)r * N_NODES * 8, Mfinal + r, x, h);
        }
    }

    // ---- Decoder MLP: out = relu(BN(h@W_d1)) @ W_d2 ----
    mgemm(h, wd1_hi, wd1_lo, t1, N_NODES, D_F, HID_F, nullptr, nullptr);
    hipMemsetAsync(sums, 0, 256 * 4, stream);
    bn_stats_kernel<<<(N_NODES + 127) / 128, 256, 0, stream>>>(t1, sums, N_NODES);
    bn_final_kernel<<<1, 128, 0, stream>>>(sums, g_d, b_d, scale, bias, 1.0f / N_NODES);
    {
        dim3 grid((N_NODES + 127) / 128, OUT_F / 64);
        gemm_kernel<true><<<grid, 256, 0, stream>>>(t1, W_d2, out, N_NODES, OUT_F, HID_F, scale, bias);
    }
}